// Round 1
// 1118.219 us; speedup vs baseline: 1.1189x; 1.1189x over previous
//
#include <hip/hip_runtime.h>
#include <hip/hip_bf16.h>
#include <stdint.h>
#include <stddef.h>

// Problem constants
#define DIM    4096      // EMBED_DIM == OUT_FEATURES == in_features
#define MROWS  8192      // B*S = 4*2048
#define NCW    16384
#define NTILES 4
#define RPT    1024      // rows per tile

// 256x256 8-phase GEMM geometry
#define BM 256
#define BN 256
#define BK 64
#define NT (DIM / BK)    // 64 K-tiles

typedef __attribute__((ext_vector_type(8))) short bf16x8;
typedef __attribute__((ext_vector_type(4))) float f32x4;

__device__ __forceinline__ uint16_t f2bf(float f) {
  union { float f; uint32_t u; } a; a.f = f;
  uint32_t u = a.u;
  u += 0x7fffu + ((u >> 16) & 1u);   // RTNE
  return (uint16_t)(u >> 16);
}

__device__ __forceinline__ void gl2lds16(const void* g, void* l) {
  __builtin_amdgcn_global_load_lds(
      (const __attribute__((address_space(1))) void*)g,
      (__attribute__((address_space(3))) void*)l, 16, 0, 0);
}

// Swizzled LDS fragment read from a 256x32-bf16 half-tile (16 KiB).
// Linear byte = r*64 + q*16; XOR bits[6:4] with bits[9:7] (involution).
// 16 lanes of a quad (16 consecutive rows, fixed q) spread over all 8
// bank-groups 2x each -> conflict-free ds_read_b128.
__device__ __forceinline__ bf16x8 lds_frag(const uint16_t* base, int r, int q) {
  int y = (r << 6) | (q << 4);
  y ^= ((y >> 7) & 7) << 4;
  return *(const bf16x8*)((const char*)base + y);
}

// ---------------------------------------------------------------------------
// Detect whether the 4096 indices arrived as int64 (odd dwords all zero) or
// int32. Writes 1 (int64) / 0 (int32) into *flag. Runs every launch.
// ---------------------------------------------------------------------------
__global__ void detect_idx_kernel(const uint32_t* __restrict__ inds,
                                  int* __restrict__ flag) {
  __shared__ int bad;
  if (threadIdx.x == 0) bad = 0;
  __syncthreads();
  int viol = 0;
  for (int k = threadIdx.x; k < 2048; k += 256) {
    uint32_t lo = inds[2 * k];
    uint32_t hi = inds[2 * k + 1];
    if (hi != 0u || lo >= (uint32_t)NCW) viol = 1;
  }
  if (viol) atomicAdd(&bad, 1);
  __syncthreads();
  if (threadIdx.x == 0) flag[0] = (bad == 0) ? 1 : 0;
}

// ---------------------------------------------------------------------------
// x fp32 -> bf16, 8 elems/thread, fully coalesced.
// ---------------------------------------------------------------------------
__global__ void cvt_x_kernel(const float* __restrict__ in,
                             uint16_t* __restrict__ out) {
  size_t i = ((size_t)blockIdx.x * 256 + threadIdx.x) * 8;
  float4 v0 = *(const float4*)(in + i);
  float4 v1 = *(const float4*)(in + i + 4);
  uint4 o;
  o.x = (uint32_t)f2bf(v0.x) | ((uint32_t)f2bf(v0.y) << 16);
  o.y = (uint32_t)f2bf(v0.z) | ((uint32_t)f2bf(v0.w) << 16);
  o.z = (uint32_t)f2bf(v1.x) | ((uint32_t)f2bf(v1.y) << 16);
  o.w = (uint32_t)f2bf(v1.z) | ((uint32_t)f2bf(v1.w) << 16);
  *(uint4*)(out + i) = o;
}

// ---------------------------------------------------------------------------
// Gather codeword rows by index, convert to bf16. One block per output row.
// ---------------------------------------------------------------------------
__global__ void gather_cw_kernel(const float* __restrict__ cw,
                                 const void* __restrict__ inds,
                                 const int* __restrict__ flag,
                                 uint16_t* __restrict__ out) {
  const int o = blockIdx.x;  // 0..4095
  long long idx;
  if (flag[0]) idx = ((const long long*)inds)[o];
  else         idx = (long long)((const int*)inds)[o];
  const float* src = cw + (size_t)idx * DIM;
  uint16_t* dst = out + (size_t)o * DIM;
  for (int c = 0; c < 4; c++) {
    int e = c * 1024 + threadIdx.x * 4;
    float4 v = *(const float4*)(src + e);
    uint2 w;
    w.x = (uint32_t)f2bf(v.x) | ((uint32_t)f2bf(v.y) << 16);
    w.y = (uint32_t)f2bf(v.z) | ((uint32_t)f2bf(v.w) << 16);
    *(uint2*)(dst + e) = w;
  }
}

// ---------------------------------------------------------------------------
// rotations[t][d][e] fp32 -> Rt[t][e][d] bf16  (transposed so the decode GEMM
// is B^T-form: K contiguous). 32x32 tiles, LDS staging, +1 pad.
// ---------------------------------------------------------------------------
__global__ void rot_transpose_kernel(const float* __restrict__ R,
                                     uint16_t* __restrict__ Rt) {
  __shared__ float tile[32][33];
  const int t = blockIdx.z;
  const int e0 = blockIdx.x * 32;
  const int d0 = blockIdx.y * 32;
  const float* Rp = R + (size_t)t * DIM * DIM;
  uint16_t* Rtp = Rt + (size_t)t * DIM * DIM;
  for (int i = threadIdx.y; i < 32; i += 8)
    tile[i][threadIdx.x] = Rp[(size_t)(d0 + i) * DIM + (e0 + threadIdx.x)];
  __syncthreads();
  for (int i = threadIdx.y; i < 32; i += 8)
    Rtp[(size_t)(e0 + i) * DIM + (d0 + threadIdx.x)] = f2bf(tile[threadIdx.x][i]);
}

// ---------------------------------------------------------------------------
// 256x256 / BK=64 8-phase bf16 GEMM, B^T input: C[M,N] = A[M,K] @ B[N,K]^T
// 512 threads = 8 waves (2M x 4N); wave owns 128x64 = 8x4 MFMA frags.
// LDS 128 KiB: A/B double-buffered, each K-tile split into two 256x32 K-step
// halves (so each half is a contiguous 16 KiB global_load_lds target).
// Per K-tile 4 phases: {ds_read frag subtile | stage one half of next tile |
// barrier | lgkmcnt(0) | setprio(1) 16xMFMA setprio(0) | [vmcnt(4)] barrier}.
// vmcnt(4) only at phases 1 and 3 -> 4-8 loads always in flight, never 0.
// T2 swizzle: LDS written linearly (global_load_lds), source address
// pre-swizzled per-lane; ds_read applies the same XOR involution.
// MODE 0 (decode): B per-tile (t = m0>>10), epilogue *scales[t], bf16 out.
// MODE 1 (output): epilogue +bias[col], fp32 out.
// ---------------------------------------------------------------------------
template <int MODE>
__global__ __launch_bounds__(512, 2)
void gemm256(const uint16_t* __restrict__ A,
             const uint16_t* __restrict__ B,
             const float* __restrict__ sv,   // scales (MODE 0) or bias (MODE 1)
             void* __restrict__ Cout) {
  __shared__ __align__(16) uint16_t As[2][2][BM * 32];  // [buf][ks][256*32]
  __shared__ __align__(16) uint16_t Bs[2][2][BN * 32];

  const int tid  = threadIdx.x;
  const int wave = tid >> 6;
  const int lane = tid & 63;
  const int quad = lane >> 4;
  const int lr   = lane & 15;
  const int wm   = (wave >> 2) * 128;   // 0 or 128
  const int wn   = (wave & 3) * 64;     // 0,64,128,192

  // T1: bijective XCD swizzle (gridDim.x % 8 == 0 for both modes)
  const int nwg = gridDim.x;
  const int bid = blockIdx.x;
  const int wg  = (bid & 7) * (nwg >> 3) + (bid >> 3);
  const int bx  = wg & 15;              // N/BN == 16
  const int by  = wg >> 4;
  const int m0  = by * BM;
  const int n0  = bx * BN;

  const uint16_t* Bp = B;
  float scale = 1.0f;
  if (MODE == 0) {
    const int t = m0 >> 10;             // 1024 rows per tile
    Bp = B + (size_t)t * DIM * DIM;
    scale = sv[t];
  }

  // Staging geometry: this thread's two linear 16B LDS chunks, and the
  // pre-swizzled global source element offsets for them (rule #21: linear
  // dest + inverse-swizzled source + swizzle on read; XOR is an involution).
  const int y0  = tid << 4;
  const int y1  = (512 + tid) << 4;
  const int gy0 = y0 ^ (((y0 >> 7) & 7) << 4);
  const int gy1 = y1 ^ (((y1 >> 7) & 7) << 4);
  const size_t ao0 = (size_t)(gy0 >> 6) * DIM + (size_t)((gy0 >> 4) & 3) * 8;
  const size_t ao1 = (size_t)(gy1 >> 6) * DIM + (size_t)((gy1 >> 4) & 3) * 8;
  const int ld0 = (wave * 64) * 8;          // wave-uniform LDS elem offset
  const int ld1 = 4096 + (wave * 64) * 8;

  const uint16_t* Ag = A  + (size_t)m0 * DIM;
  const uint16_t* Bg = Bp + (size_t)n0 * DIM;

#define STG(gb, kc, lh)                          \
  do {                                           \
    gl2lds16((gb) + ao0 + (kc), (lh) + ld0);     \
    gl2lds16((gb) + ao1 + (kc), (lh) + ld1);     \
  } while (0)

  f32x4 acc[8][4];
#pragma unroll
  for (int i = 0; i < 8; i++)
#pragma unroll
    for (int j = 0; j < 4; j++) acc[i][j] = f32x4{0.f, 0.f, 0.f, 0.f};

  // Prologue: stage K-tile 0 (order: A-ks0, B-ks0, A-ks1, B-ks1), wait for
  // the ks0 halves only (vmcnt(4)) -> ks1 halves stay in flight.
  STG(Ag, 0,  As[0][0]);
  STG(Bg, 0,  Bs[0][0]);
  STG(Ag, 32, As[0][1]);
  STG(Bg, 32, Bs[0][1]);
  asm volatile("s_waitcnt vmcnt(4)" ::: "memory");
  __builtin_amdgcn_s_barrier();

  int cur = 0;
  bf16x8 b[4];   // B frags live across the two phases of one K-step

#define PHASE(KS, MH, STAGE_STMT, DO_VM)                                      \
  do {                                                                        \
    const uint16_t* Ab = As[cur][KS];                                         \
    bf16x8 a[4];                                                              \
    _Pragma("unroll")                                                         \
    for (int j = 0; j < 4; ++j)                                               \
      a[j] = lds_frag(Ab, wm + ((MH)*4 + j) * 16 + lr, quad);                 \
    if ((MH) == 0) {                                                          \
      const uint16_t* Bb = Bs[cur][KS];                                       \
      _Pragma("unroll")                                                       \
      for (int j = 0; j < 4; ++j)                                             \
        b[j] = lds_frag(Bb, wn + j * 16 + lr, quad);                          \
    }                                                                         \
    STAGE_STMT;                                                               \
    __builtin_amdgcn_s_barrier();                                             \
    asm volatile("s_waitcnt lgkmcnt(0)" ::: "memory");                        \
    __builtin_amdgcn_sched_barrier(0);                                        \
    __builtin_amdgcn_s_setprio(1);                                            \
    _Pragma("unroll")                                                         \
    for (int j = 0; j < 4; ++j)                                               \
      _Pragma("unroll")                                                       \
      for (int n = 0; n < 4; ++n)                                             \
        acc[(MH)*4 + j][n] = __builtin_amdgcn_mfma_f32_16x16x32_bf16(         \
            a[j], b[n], acc[(MH)*4 + j][n], 0, 0, 0);                         \
    __builtin_amdgcn_s_setprio(0);                                            \
    if (DO_VM) asm volatile("s_waitcnt vmcnt(4)" ::: "memory");               \
    __builtin_amdgcn_s_barrier();                                             \
  } while (0)

  for (int kt = 0; kt < NT; ++kt) {
    // Last tile re-stages itself (clamped) to keep vmcnt accounting uniform.
    const int kn = (kt + 1 < NT) ? (kt + 1) * BK : kt * BK;
    PHASE(0, 0, STG(Ag, kn,      As[cur ^ 1][0]), 0);
    PHASE(0, 1, STG(Bg, kn,      Bs[cur ^ 1][0]), 1);
    PHASE(1, 0, STG(Ag, kn + 32, As[cur ^ 1][1]), 0);
    PHASE(1, 1, STG(Bg, kn + 32, Bs[cur ^ 1][1]), 1);
    cur ^= 1;
  }
  asm volatile("s_waitcnt vmcnt(0)" ::: "memory");

#undef PHASE
#undef STG

  // Epilogue — C/D layout: col = lane&15, row = quad*4 + reg
  if (MODE == 0) {
    uint16_t* C = (uint16_t*)Cout;
#pragma unroll
    for (int mi = 0; mi < 8; mi++)
#pragma unroll
      for (int ni = 0; ni < 4; ni++)
#pragma unroll
        for (int r = 0; r < 4; r++) {
          int row = m0 + wm + mi * 16 + quad * 4 + r;
          int col = n0 + wn + ni * 16 + lr;
          C[(size_t)row * DIM + col] = f2bf(acc[mi][ni][r] * scale);
        }
  } else {
    float* C = (float*)Cout;
#pragma unroll
    for (int mi = 0; mi < 8; mi++)
#pragma unroll
      for (int ni = 0; ni < 4; ni++)
#pragma unroll
        for (int r = 0; r < 4; r++) {
          int row = m0 + wm + mi * 16 + quad * 4 + r;
          int col = n0 + wn + ni * 16 + lr;
          C[(size_t)row * DIM + col] = acc[mi][ni][r] + sv[col];
        }
  }
}

// ---------------------------------------------------------------------------
extern "C" void kernel_launch(void* const* d_in, const int* in_sizes, int n_in,
                              void* d_out, int out_size, void* d_ws,
                              size_t ws_size, hipStream_t stream) {
  const float* x      = (const float*)d_in[0];
  const float* cw     = (const float*)d_in[1];
  const void*  inds   = d_in[2];
  const float* rot    = (const float*)d_in[3];
  const float* scales = (const float*)d_in[4];
  const float* bias   = (const float*)d_in[5];
  float* out = (float*)d_out;

  // workspace layout (256 MiB + 256 B)
  char* ws = (char*)d_ws;
  int*      flag = (int*)ws;                                   // 4 B (pad 256)
  uint16_t* Xb   = (uint16_t*)(ws + 256);                      // 64 MiB
  uint16_t* Cgb  = (uint16_t*)(ws + 256 + (size_t)64  * 1024 * 1024); // 32 MiB
  uint16_t* Rt   = (uint16_t*)(ws + 256 + (size_t)96  * 1024 * 1024); // 128 MiB
  uint16_t* Wb   = (uint16_t*)(ws + 256 + (size_t)224 * 1024 * 1024); // 32 MiB

  detect_idx_kernel<<<1, 256, 0, stream>>>((const uint32_t*)inds, flag);

  // x -> bf16 : 33,554,432 elems / 8 per thread / 256 per block = 16384 blocks
  cvt_x_kernel<<<16384, 256, 0, stream>>>(x, Xb);

  gather_cw_kernel<<<DIM, 256, 0, stream>>>(cw, inds, flag, Cgb);

  rot_transpose_kernel<<<dim3(DIM / 32, DIM / 32, NTILES), dim3(32, 8), 0,
                         stream>>>(rot, Rt);

  // decode: Wb[o,e] = scales[t] * sum_d Cgb[o,d] * Rt[t][e,d]
  gemm256<0><<<dim3((DIM / BN) * (DIM / BM)), 512, 0, stream>>>(
      Cgb, Rt, scales, (void*)Wb);

  // out[m,o] = sum_e Xb[m,e] * Wb[o,e] + bias[o]
  gemm256<1><<<dim3((DIM / BN) * (MROWS / BM)), 512, 0, stream>>>(
      Xb, Wb, bias, (void*)out);
}

// Round 2
// 1010.672 us; speedup vs baseline: 1.2379x; 1.1064x over previous
//
#include <hip/hip_runtime.h>
#include <hip/hip_bf16.h>
#include <stdint.h>
#include <stddef.h>

// Problem constants
#define DIM    4096      // EMBED_DIM == OUT_FEATURES == in_features
#define MROWS  8192      // B*S = 4*2048
#define NCW    16384
#define NTILES 4
#define RPT    1024      // rows per tile

// 256x256 GEMM geometry
#define BM 256
#define BN 256
#define BK 64
#define NT (DIM / BK)    // 64 K-tiles

typedef __attribute__((ext_vector_type(8))) short bf16x8;
typedef __attribute__((ext_vector_type(4))) float f32x4;

__device__ __forceinline__ uint16_t f2bf(float f) {
  union { float f; uint32_t u; } a; a.f = f;
  uint32_t u = a.u;
  u += 0x7fffu + ((u >> 16) & 1u);   // RTNE
  return (uint16_t)(u >> 16);
}

__device__ __forceinline__ void gl2lds16(const void* g, void* l) {
  __builtin_amdgcn_global_load_lds(
      (const __attribute__((address_space(1))) void*)g,
      (__attribute__((address_space(3))) void*)l, 16, 0, 0);
}

// Swizzled LDS fragment read from a 256x32-bf16 half-tile (16 KiB).
// Linear byte = r*64 + q*16; XOR bits[6:4] with bits[9:7] (involution).
// Verified round 1: SQ_LDS_BANK_CONFLICT == 0.
__device__ __forceinline__ bf16x8 lds_frag(const uint16_t* base, int r, int q) {
  int y = (r << 6) | (q << 4);
  y ^= ((y >> 7) & 7) << 4;
  return *(const bf16x8*)((const char*)base + y);
}

// ---------------------------------------------------------------------------
// Detect whether the 4096 indices arrived as int64 (odd dwords all zero) or
// int32. Writes 1 (int64) / 0 (int32) into *flag. Runs every launch.
// ---------------------------------------------------------------------------
__global__ void detect_idx_kernel(const uint32_t* __restrict__ inds,
                                  int* __restrict__ flag) {
  __shared__ int bad;
  if (threadIdx.x == 0) bad = 0;
  __syncthreads();
  int viol = 0;
  for (int k = threadIdx.x; k < 2048; k += 256) {
    uint32_t lo = inds[2 * k];
    uint32_t hi = inds[2 * k + 1];
    if (hi != 0u || lo >= (uint32_t)NCW) viol = 1;
  }
  if (viol) atomicAdd(&bad, 1);
  __syncthreads();
  if (threadIdx.x == 0) flag[0] = (bad == 0) ? 1 : 0;
}

// ---------------------------------------------------------------------------
// x fp32 -> bf16, 8 elems/thread, fully coalesced.
// ---------------------------------------------------------------------------
__global__ void cvt_x_kernel(const float* __restrict__ in,
                             uint16_t* __restrict__ out) {
  size_t i = ((size_t)blockIdx.x * 256 + threadIdx.x) * 8;
  float4 v0 = *(const float4*)(in + i);
  float4 v1 = *(const float4*)(in + i + 4);
  uint4 o;
  o.x = (uint32_t)f2bf(v0.x) | ((uint32_t)f2bf(v0.y) << 16);
  o.y = (uint32_t)f2bf(v0.z) | ((uint32_t)f2bf(v0.w) << 16);
  o.z = (uint32_t)f2bf(v1.x) | ((uint32_t)f2bf(v1.y) << 16);
  o.w = (uint32_t)f2bf(v1.z) | ((uint32_t)f2bf(v1.w) << 16);
  *(uint4*)(out + i) = o;
}

// ---------------------------------------------------------------------------
// Gather codeword rows by index, convert to bf16. One block per output row.
// ---------------------------------------------------------------------------
__global__ void gather_cw_kernel(const float* __restrict__ cw,
                                 const void* __restrict__ inds,
                                 const int* __restrict__ flag,
                                 uint16_t* __restrict__ out) {
  const int o = blockIdx.x;  // 0..4095
  long long idx;
  if (flag[0]) idx = ((const long long*)inds)[o];
  else         idx = (long long)((const int*)inds)[o];
  const float* src = cw + (size_t)idx * DIM;
  uint16_t* dst = out + (size_t)o * DIM;
  for (int c = 0; c < 4; c++) {
    int e = c * 1024 + threadIdx.x * 4;
    float4 v = *(const float4*)(src + e);
    uint2 w;
    w.x = (uint32_t)f2bf(v.x) | ((uint32_t)f2bf(v.y) << 16);
    w.y = (uint32_t)f2bf(v.z) | ((uint32_t)f2bf(v.w) << 16);
    *(uint2*)(dst + e) = w;
  }
}

// ---------------------------------------------------------------------------
// rotations[t][d][e] fp32 -> Rt[t][e][d] bf16, 64x64 tiles.
// Reads float4-coalesced; writes uint4 (8 bf16, 16 B/lane, 128 B per 8 lanes).
// LDS 64x65 fp32; write-phase reads are 2-way conflict max (free).
// ---------------------------------------------------------------------------
__global__ void rot_transpose_kernel(const float* __restrict__ R,
                                     uint16_t* __restrict__ Rt) {
  __shared__ float tile[64][65];
  const int t = blockIdx.z;
  const int e0 = blockIdx.x * 64;
  const int d0 = blockIdx.y * 64;
  const float* Rp = R + (size_t)t * DIM * DIM;
  uint16_t* Rtp = Rt + (size_t)t * DIM * DIM;

  const int tx = threadIdx.x & 15;   // float4 col within tile
  const int ty = threadIdx.x >> 4;   // row 0..15
#pragma unroll
  for (int i = 0; i < 4; ++i) {
    int d = ty + i * 16;
    float4 v = *(const float4*)(Rp + (size_t)(d0 + d) * DIM + e0 + tx * 4);
    tile[d][tx * 4 + 0] = v.x;
    tile[d][tx * 4 + 1] = v.y;
    tile[d][tx * 4 + 2] = v.z;
    tile[d][tx * 4 + 3] = v.w;
  }
  __syncthreads();

  const int g = threadIdx.x & 7;     // d-group (8 elems)
  const int e = threadIdx.x >> 3;    // 0..31
#pragma unroll
  for (int i = 0; i < 2; ++i) {
    int ee = e + i * 32;
    uint32_t w[4];
#pragma unroll
    for (int p = 0; p < 4; ++p) {
      float lo = tile[g * 8 + 2 * p    ][ee];
      float hi = tile[g * 8 + 2 * p + 1][ee];
      w[p] = (uint32_t)f2bf(lo) | ((uint32_t)f2bf(hi) << 16);
    }
    *(uint4*)(Rtp + (size_t)(e0 + ee) * DIM + d0 + g * 8) = *(uint4*)w;
  }
}

// ---------------------------------------------------------------------------
// 256x256 / BK=64 bf16 GEMM, B^T input: C[M,N] = A[M,K] @ B[N,K]^T
// 512 threads = 8 waves (2M x 4N); wave owns 128x64 = 8x4 MFMA frags.
// 4 phases per K-tile, ONE barrier per phase, register prefetch one phase
// ahead (ping-pong frag sets a0/a1, b0/b1): the ds_reads issued in phase p
// complete during phase p's MFMA and feed phase p+1's MFMA -> LDS pipe and
// MFMA pipe overlap. lgkm waits are compiler-managed (precise counted waits).
// Counted vmcnt(2) at ends of phases 1 and 3 (before the barrier guarding
// the freshly staged half-tiles the NEXT phase's prefetch reads).
// Steady-state outstanding stage-loads: 4 -> 6 -> 2 (never drained to 0).
// MODE 0 (decode): B per-tile (t = m0>>10), epilogue *scales[t], bf16 out.
// MODE 1 (output): epilogue +bias[col], fp32 out.
// ---------------------------------------------------------------------------
template <int MODE>
__global__ __launch_bounds__(512, 2)
void gemm256(const uint16_t* __restrict__ A,
             const uint16_t* __restrict__ B,
             const float* __restrict__ sv,   // scales (MODE 0) or bias (MODE 1)
             void* __restrict__ Cout) {
  __shared__ __align__(16) uint16_t As[2][2][BM * 32];  // [buf][ks][256*32]
  __shared__ __align__(16) uint16_t Bs[2][2][BN * 32];

  const int tid  = threadIdx.x;
  const int wave = tid >> 6;
  const int lane = tid & 63;
  const int quad = lane >> 4;
  const int lr   = lane & 15;
  const int wm   = (wave >> 2) * 128;   // 0 or 128
  const int wn   = (wave & 3) * 64;     // 0,64,128,192

  // T1: bijective XCD swizzle (gridDim.x % 8 == 0 for both modes)
  const int nwg = gridDim.x;
  const int bid = blockIdx.x;
  const int wg  = (bid & 7) * (nwg >> 3) + (bid >> 3);
  const int bx  = wg & 15;              // N/BN == 16
  const int by  = wg >> 4;
  const int m0  = by * BM;
  const int n0  = bx * BN;

  const uint16_t* Bp = B;
  float scale = 1.0f;
  if (MODE == 0) {
    const int t = m0 >> 10;             // 1024 rows per tile
    Bp = B + (size_t)t * DIM * DIM;
    scale = sv[t];
  }

  // Staging geometry: linear LDS dest (global_load_lds), pre-swizzled global
  // source (rule #21; XOR is an involution). Verified round 1.
  const int y0  = tid << 4;
  const int y1  = (512 + tid) << 4;
  const int gy0 = y0 ^ (((y0 >> 7) & 7) << 4);
  const int gy1 = y1 ^ (((y1 >> 7) & 7) << 4);
  const size_t ao0 = (size_t)(gy0 >> 6) * DIM + (size_t)((gy0 >> 4) & 3) * 8;
  const size_t ao1 = (size_t)(gy1 >> 6) * DIM + (size_t)((gy1 >> 4) & 3) * 8;
  const int ld0 = (wave * 64) * 8;          // wave-uniform LDS elem offset
  const int ld1 = 4096 + (wave * 64) * 8;

  const uint16_t* Ag = A  + (size_t)m0 * DIM;
  const uint16_t* Bg = Bp + (size_t)n0 * DIM;

#define STG(gb, kc, lh)                          \
  do {                                           \
    gl2lds16((gb) + ao0 + (kc), (lh) + ld0);     \
    gl2lds16((gb) + ao1 + (kc), (lh) + ld1);     \
  } while (0)

#define LDA(dst, half, mh)                                       \
  do {                                                           \
    const uint16_t* _p = (half);                                 \
    _Pragma("unroll")                                            \
    for (int j = 0; j < 4; ++j)                                  \
      dst[j] = lds_frag(_p, wm + ((mh) * 4 + j) * 16 + lr, quad);\
  } while (0)

#define LDB(dst, half)                                           \
  do {                                                           \
    const uint16_t* _p = (half);                                 \
    _Pragma("unroll")                                            \
    for (int j = 0; j < 4; ++j)                                  \
      dst[j] = lds_frag(_p, wn + j * 16 + lr, quad);             \
  } while (0)

#define MFMA16(MH, AA, BB)                                            \
  do {                                                                \
    __builtin_amdgcn_s_setprio(1);                                    \
    _Pragma("unroll")                                                 \
    for (int j = 0; j < 4; ++j)                                       \
      _Pragma("unroll")                                               \
      for (int n = 0; n < 4; ++n)                                     \
        acc[(MH) * 4 + j][n] = __builtin_amdgcn_mfma_f32_16x16x32_bf16(\
            AA[j], BB[n], acc[(MH) * 4 + j][n], 0, 0, 0);             \
    __builtin_amdgcn_s_setprio(0);                                    \
  } while (0)

  f32x4 acc[8][4];
#pragma unroll
  for (int i = 0; i < 8; i++)
#pragma unroll
    for (int j = 0; j < 4; j++) acc[i][j] = f32x4{0.f, 0.f, 0.f, 0.f};

  bf16x8 a0[4], a1[4], b0[4], b1[4];

  // Prologue: stage K-tile 0 (A0,B0,A1,B1 -> buf0), wait ks0 halves only,
  // prefetch phase-1 frags.
  STG(Ag, 0,  As[0][0]);
  STG(Bg, 0,  Bs[0][0]);
  STG(Ag, 32, As[0][1]);
  STG(Bg, 32, Bs[0][1]);
  asm volatile("s_waitcnt vmcnt(4)" ::: "memory");
  __builtin_amdgcn_s_barrier();
  LDA(a0, As[0][0], 0);
  LDB(b0, Bs[0][0]);

  int cur = 0;
  for (int kt = 0; kt < NT; ++kt) {
    // Last tile re-stages itself (clamped) to keep vmcnt accounting uniform.
    const int kn = (kt + 1 < NT) ? (kt + 1) * BK : kt * BK;

    // ---- phase 1: MFMA mh0/ks0; prefetch a1 <- A[cur][0] mh1; stage A0'
    __builtin_amdgcn_s_barrier();
    LDA(a1, As[cur][0], 1);
    STG(Ag, kn, As[cur ^ 1][0]);
    MFMA16(0, a0, b0);
    asm volatile("s_waitcnt vmcnt(2)" ::: "memory");  // drain A1,B1 of cur tile

    // ---- phase 2: MFMA mh1/ks0; prefetch a0 <- A[cur][1] mh0, b1 <- B[cur][1]; stage B0'
    __builtin_amdgcn_s_barrier();
    LDA(a0, As[cur][1], 0);
    LDB(b1, Bs[cur][1]);
    STG(Bg, kn, Bs[cur ^ 1][0]);
    MFMA16(1, a1, b0);

    // ---- phase 3: MFMA mh0/ks1; prefetch a1 <- A[cur][1] mh1; stage A1'
    __builtin_amdgcn_s_barrier();
    LDA(a1, As[cur][1], 1);
    STG(Ag, kn + 32, As[cur ^ 1][1]);
    MFMA16(0, a0, b1);
    asm volatile("s_waitcnt vmcnt(2)" ::: "memory");  // drain A0',B0'

    // ---- phase 4: MFMA mh1/ks1; prefetch a0,b0 <- next tile ks0; stage B1'
    __builtin_amdgcn_s_barrier();
    LDA(a0, As[cur ^ 1][0], 0);
    LDB(b0, Bs[cur ^ 1][0]);
    STG(Bg, kn + 32, Bs[cur ^ 1][1]);
    MFMA16(1, a1, b1);

    cur ^= 1;
  }
  asm volatile("s_waitcnt vmcnt(0)" ::: "memory");

#undef MFMA16
#undef LDB
#undef LDA
#undef STG

  // Epilogue — C/D layout: col = lane&15, row = quad*4 + reg
  if (MODE == 0) {
    uint16_t* C = (uint16_t*)Cout;
#pragma unroll
    for (int mi = 0; mi < 8; mi++)
#pragma unroll
      for (int ni = 0; ni < 4; ni++)
#pragma unroll
        for (int r = 0; r < 4; r++) {
          int row = m0 + wm + mi * 16 + quad * 4 + r;
          int col = n0 + wn + ni * 16 + lr;
          C[(size_t)row * DIM + col] = f2bf(acc[mi][ni][r] * scale);
        }
  } else {
    float* C = (float*)Cout;
#pragma unroll
    for (int mi = 0; mi < 8; mi++)
#pragma unroll
      for (int ni = 0; ni < 4; ni++)
#pragma unroll
        for (int r = 0; r < 4; r++) {
          int row = m0 + wm + mi * 16 + quad * 4 + r;
          int col = n0 + wn + ni * 16 + lr;
          C[(size_t)row * DIM + col] = acc[mi][ni][r] + sv[col];
        }
  }
}

// ---------------------------------------------------------------------------
extern "C" void kernel_launch(void* const* d_in, const int* in_sizes, int n_in,
                              void* d_out, int out_size, void* d_ws,
                              size_t ws_size, hipStream_t stream) {
  const float* x      = (const float*)d_in[0];
  const float* cw     = (const float*)d_in[1];
  const void*  inds   = d_in[2];
  const float* rot    = (const float*)d_in[3];
  const float* scales = (const float*)d_in[4];
  const float* bias   = (const float*)d_in[5];
  float* out = (float*)d_out;

  // workspace layout (256 MiB + 256 B)
  char* ws = (char*)d_ws;
  int*      flag = (int*)ws;                                   // 4 B (pad 256)
  uint16_t* Xb   = (uint16_t*)(ws + 256);                      // 64 MiB
  uint16_t* Cgb  = (uint16_t*)(ws + 256 + (size_t)64  * 1024 * 1024); // 32 MiB
  uint16_t* Rt   = (uint16_t*)(ws + 256 + (size_t)96  * 1024 * 1024); // 128 MiB
  uint16_t* Wb   = (uint16_t*)(ws + 256 + (size_t)224 * 1024 * 1024); // 32 MiB

  detect_idx_kernel<<<1, 256, 0, stream>>>((const uint32_t*)inds, flag);

  // x -> bf16 : 33,554,432 elems / 8 per thread / 256 per block = 16384 blocks
  cvt_x_kernel<<<16384, 256, 0, stream>>>(x, Xb);

  gather_cw_kernel<<<DIM, 256, 0, stream>>>(cw, inds, flag, Cgb);

  rot_transpose_kernel<<<dim3(DIM / 64, DIM / 64, NTILES), 256, 0, stream>>>(
      rot, Rt);

  // decode: Wb[o,e] = scales[t] * sum_d Cgb[o,d] * Rt[t][e,d]
  gemm256<0><<<dim3((DIM / BN) * (DIM / BM)), 512, 0, stream>>>(
      Cgb, Rt, scales, (void*)Wb);

  // out[m,o] = sum_e Xb[m,e] * Wb[o,e] + bias[o]
  gemm256<1><<<dim3((DIM / BN) * (MROWS / BM)), 512, 0, stream>>>(
      Xb, Wb, bias, (void*)out);
}